// Round 1
// baseline (239.273 us; speedup 1.0000x reference)
//
#include <hip/hip_runtime.h>
#include <math.h>

// Problem constants (match reference)
#define BG 256   // graphs
#define NN 512   // nodes per graph
#define DD 256   // feature dim
#define KK 256   // nodes kept per graph

// ---------------------------------------------------------------------------
// Kernel 1: score[n] = tanh( dot(x[n,:], w) / ||w|| )
// One wave (64 lanes) per row: lane l loads x[row, 4l..4l+3] as float4
// -> 64 lanes x 16 B = 1024 B = exactly one row, perfectly coalesced.
// ---------------------------------------------------------------------------
__global__ __launch_bounds__(256) void score_kernel(const float* __restrict__ x,
                                                    const float* __restrict__ w,
                                                    float* __restrict__ score,
                                                    int nrows) {
    const int lane   = threadIdx.x & 63;
    const int wid    = blockIdx.x * (blockDim.x >> 6) + (threadIdx.x >> 6);
    const int nwaves = gridDim.x * (blockDim.x >> 6);

    // w fragment lives in registers for the whole kernel
    const float4 w4 = *reinterpret_cast<const float4*>(w + lane * 4);

    // ||w||: wave-reduce dot(w,w)
    float nw = w4.x * w4.x + w4.y * w4.y + w4.z * w4.z + w4.w * w4.w;
#pragma unroll
    for (int off = 32; off >= 1; off >>= 1) nw += __shfl_xor(nw, off);
    const float inv_nrm = rsqrtf(nw);

    for (int row = wid; row < nrows; row += nwaves) {
        const float4 x4 = *reinterpret_cast<const float4*>(x + (size_t)row * DD + lane * 4);
        float d = x4.x * w4.x + x4.y * w4.y + x4.z * w4.z + x4.w * w4.w;
#pragma unroll
        for (int off = 32; off >= 1; off >>= 1) d += __shfl_xor(d, off);
        if (lane == 0) score[row] = tanhf(d * inv_nrm);
    }
}

// ---------------------------------------------------------------------------
// Kernel 2: per-graph top-K selection + gated mean pool.
// One block of 256 threads per graph. Bitonic sort (descending) of the 512
// scores in LDS to find the K-th value; exact-K tie handling matching
// jax.lax.top_k (stable: lower index wins on equal values); then thread d
// accumulates sum over selected rows of s[i]*x[i,d] (coalesced across d).
// ---------------------------------------------------------------------------
__global__ __launch_bounds__(256) void pool_kernel(const float* __restrict__ x,
                                                   const float* __restrict__ score,
                                                   float* __restrict__ out) {
    __shared__ float sorig[NN];
    __shared__ float ssort[NN];
    __shared__ int   list[KK];
    __shared__ float sval[KK];
    __shared__ int   cnt_gt;
    __shared__ int   cnt_sel;

    const int b = blockIdx.x;
    const int t = threadIdx.x;

    const float* sg = score + b * NN;
    sorig[t]       = sg[t];
    sorig[t + 256] = sg[t + 256];
    ssort[t]       = sorig[t];
    ssort[t + 256] = sorig[t + 256];
    if (t == 0) { cnt_gt = 0; cnt_sel = 0; }
    __syncthreads();

    // Bitonic sort, final order descending (larger values at lower index).
    for (int k = 2; k <= NN; k <<= 1) {
        for (int j = k >> 1; j > 0; j >>= 1) {
#pragma unroll
            for (int r = 0; r < 2; ++r) {
                const int i = t + r * 256;
                const int p = i ^ j;
                if (p > i) {
                    const bool up = ((i & k) == 0);   // up-subsequence => descending
                    const float a = ssort[i];
                    const float c = ssort[p];
                    const bool sw = up ? (a < c) : (a > c);
                    if (sw) { ssort[i] = c; ssort[p] = a; }
                }
            }
            __syncthreads();
        }
    }

    const float thr = ssort[KK - 1];   // K-th largest value

    // count of strictly-greater values
    {
        int local = (ssort[t] > thr ? 1 : 0) + (ssort[t + 256] > thr ? 1 : 0);
        if (local) atomicAdd(&cnt_gt, local);
    }
    __syncthreads();
    const int need = KK - cnt_gt;      // how many ==thr ties to take (lowest index first)

    // Selection + compaction (order in list[] is irrelevant for the sum)
#pragma unroll
    for (int r = 0; r < 2; ++r) {
        const int i = t + r * 256;
        const float s = sorig[i];
        bool sel = (s > thr);
        if (!sel && s == thr) {
            // rank among ties by ascending index (rare path; cheap LDS scan)
            int rank = 0;
            for (int j2 = 0; j2 < i; ++j2) rank += (sorig[j2] == thr) ? 1 : 0;
            sel = (rank < need);
        }
        if (sel) {
            const int pos = atomicAdd(&cnt_sel, 1);
            list[pos] = i;
            sval[pos] = s;
        }
    }
    __syncthreads();

    // Accumulate: thread t owns output column t. Consecutive threads read
    // consecutive floats of each selected row -> coalesced 1 KiB per row.
    const float* xg = x + (size_t)b * NN * DD;
    float acc = 0.0f;
#pragma unroll 4
    for (int kk = 0; kk < KK; ++kk) {
        const int i = list[kk];
        acc = fmaf(sval[kk], xg[(size_t)i * DD + t], acc);
    }
    out[b * DD + t] = acc * (1.0f / (float)KK);
}

extern "C" void kernel_launch(void* const* d_in, const int* in_sizes, int n_in,
                              void* d_out, int out_size, void* d_ws, size_t ws_size,
                              hipStream_t stream) {
    const float* x = (const float*)d_in[0];
    const float* w = (const float*)d_in[1];
    // d_in[2] (edge_index) and d_in[3] (batch) are dead w.r.t. the output.
    float* score = (float*)d_ws;          // 131072 floats = 512 KiB scratch
    float* out   = (float*)d_out;

    const int nrows = BG * NN;            // 131072
    score_kernel<<<2048, 256, 0, stream>>>(x, w, score, nrows);
    pool_kernel<<<BG, 256, 0, stream>>>(x, score, out);
}

// Round 2
// 234.159 us; speedup vs baseline: 1.0218x; 1.0218x over previous
//
#include <hip/hip_runtime.h>
#include <math.h>

// Problem constants (match reference)
#define BG 256   // graphs
#define NN 512   // nodes per graph
#define DD 256   // feature dim
#define KK 256   // nodes kept per graph
#define RPW 16   // rows per wave in score kernel
#define SPLIT 4  // row-chunks per graph in accumulate kernel

// ---------------------------------------------------------------------------
// Kernel 1: score[n] = tanh( dot(x[n,:], w) / ||w|| )
// Wave-per-row, float4 loads (64 lanes x 16 B = 1 KiB = one row per load).
// Each wave owns 16 CONSECUTIVE rows (16 KiB contiguous span) and processes
// them 4 at a time with independent shuffle-reduce chains for ILP.
// ---------------------------------------------------------------------------
__global__ __launch_bounds__(256) void score_kernel(const float* __restrict__ x,
                                                    const float* __restrict__ w,
                                                    float* __restrict__ score) {
    const int lane = threadIdx.x & 63;
    const int wid  = blockIdx.x * 4 + (threadIdx.x >> 6);

    const float4 w4 = *reinterpret_cast<const float4*>(w + lane * 4);

    float nw = w4.x * w4.x + w4.y * w4.y + w4.z * w4.z + w4.w * w4.w;
#pragma unroll
    for (int off = 32; off >= 1; off >>= 1) nw += __shfl_xor(nw, off);
    const float inv_nrm = rsqrtf(nw);

    const int base = wid * RPW;
    const float* xp = x + (size_t)base * DD + lane * 4;

#pragma unroll
    for (int r0 = 0; r0 < RPW; r0 += 4) {
        float d0, d1, d2, d3;
        {
            const float4 a = *reinterpret_cast<const float4*>(xp + (size_t)(r0 + 0) * DD);
            const float4 b = *reinterpret_cast<const float4*>(xp + (size_t)(r0 + 1) * DD);
            const float4 c = *reinterpret_cast<const float4*>(xp + (size_t)(r0 + 2) * DD);
            const float4 e = *reinterpret_cast<const float4*>(xp + (size_t)(r0 + 3) * DD);
            d0 = fmaf(a.x, w4.x, fmaf(a.y, w4.y, fmaf(a.z, w4.z, a.w * w4.w)));
            d1 = fmaf(b.x, w4.x, fmaf(b.y, w4.y, fmaf(b.z, w4.z, b.w * w4.w)));
            d2 = fmaf(c.x, w4.x, fmaf(c.y, w4.y, fmaf(c.z, w4.z, c.w * w4.w)));
            d3 = fmaf(e.x, w4.x, fmaf(e.y, w4.y, fmaf(e.z, w4.z, e.w * w4.w)));
        }
#pragma unroll
        for (int off = 32; off >= 1; off >>= 1) {
            d0 += __shfl_xor(d0, off);
            d1 += __shfl_xor(d1, off);
            d2 += __shfl_xor(d2, off);
            d3 += __shfl_xor(d3, off);
        }
        if (lane == 0) {
            float4 o;
            o.x = tanhf(d0 * inv_nrm);
            o.y = tanhf(d1 * inv_nrm);
            o.z = tanhf(d2 * inv_nrm);
            o.w = tanhf(d3 * inv_nrm);
            *reinterpret_cast<float4*>(score + base + r0) = o;
        }
    }
}

// ---------------------------------------------------------------------------
// Kernel 2: per-graph top-K selection. One block of 256 threads per graph.
// Bitonic sort (descending) of 512 scores in LDS -> K-th value threshold;
// exact-K tie handling matching jax.lax.top_k (stable: lower index wins).
// Emits compacted index list + score*(1/K) per graph into workspace.
// ---------------------------------------------------------------------------
__global__ __launch_bounds__(256) void select_kernel(const float* __restrict__ score,
                                                     int* __restrict__ list,
                                                     float* __restrict__ sval) {
    __shared__ float sorig[NN];
    __shared__ float ssort[NN];
    __shared__ int   cnt_gt;
    __shared__ int   cnt_sel;

    const int b = blockIdx.x;
    const int t = threadIdx.x;

    const float* sg = score + b * NN;
    sorig[t]       = sg[t];
    sorig[t + 256] = sg[t + 256];
    ssort[t]       = sorig[t];
    ssort[t + 256] = sorig[t + 256];
    if (t == 0) { cnt_gt = 0; cnt_sel = 0; }
    __syncthreads();

    for (int k = 2; k <= NN; k <<= 1) {
        for (int j = k >> 1; j > 0; j >>= 1) {
#pragma unroll
            for (int r = 0; r < 2; ++r) {
                const int i = t + r * 256;
                const int p = i ^ j;
                if (p > i) {
                    const bool up = ((i & k) == 0);
                    const float a = ssort[i];
                    const float c = ssort[p];
                    const bool sw = up ? (a < c) : (a > c);
                    if (sw) { ssort[i] = c; ssort[p] = a; }
                }
            }
            __syncthreads();
        }
    }

    const float thr = ssort[KK - 1];

    {
        int local = (ssort[t] > thr ? 1 : 0) + (ssort[t + 256] > thr ? 1 : 0);
        if (local) atomicAdd(&cnt_gt, local);
    }
    __syncthreads();
    const int need = KK - cnt_gt;   // ties at thr to take, lowest index first

    int*   lb = list + b * KK;
    float* sb = sval + b * KK;
#pragma unroll
    for (int r = 0; r < 2; ++r) {
        const int i = t + r * 256;
        const float s = sorig[i];
        bool sel = (s > thr);
        if (!sel && s == thr) {
            int rank = 0;
            for (int j2 = 0; j2 < i; ++j2) rank += (sorig[j2] == thr) ? 1 : 0;
            sel = (rank < need);
        }
        if (sel) {
            const int pos = atomicAdd(&cnt_sel, 1);
            lb[pos] = i;
            sb[pos] = s * (1.0f / (float)KK);   // fold mean divisor in here
        }
    }
}

// ---------------------------------------------------------------------------
// Kernel 3: gated mean accumulate. Grid (BG, SPLIT); 256 threads = 4 waves.
// Each wave handles 16 selected rows with full-row float4 loads (1 KiB per
// load instruction), 16-deep unrolled for latency hiding. Cross-wave LDS
// reduce, then one float atomicAdd per column (out pre-zeroed).
// ---------------------------------------------------------------------------
__global__ __launch_bounds__(256) void accum_kernel(const float* __restrict__ x,
                                                    const int* __restrict__ list,
                                                    const float* __restrict__ sval,
                                                    float* __restrict__ out) {
    const int b    = blockIdx.x;
    const int s    = blockIdx.y;
    const int wv   = threadIdx.x >> 6;
    const int lane = threadIdx.x & 63;
    const int kk0  = s * (KK / SPLIT) + wv * (KK / SPLIT / 4);   // 16 rows per wave

    const float* xg = x + (size_t)b * NN * DD;
    const int*   lb = list + b * KK + kk0;
    const float* sb = sval + b * KK + kk0;

    float4 acc = {0.f, 0.f, 0.f, 0.f};
#pragma unroll
    for (int r = 0; r < KK / SPLIT / 4; ++r) {   // 16 iterations
        const int   i  = lb[r];
        const float sv = sb[r];
        const float4 x4 = *reinterpret_cast<const float4*>(xg + (size_t)i * DD + lane * 4);
        acc.x = fmaf(sv, x4.x, acc.x);
        acc.y = fmaf(sv, x4.y, acc.y);
        acc.z = fmaf(sv, x4.z, acc.z);
        acc.w = fmaf(sv, x4.w, acc.w);
    }

    __shared__ float red[4][DD];
    *reinterpret_cast<float4*>(&red[wv][lane * 4]) = acc;
    __syncthreads();

    const int t = threadIdx.x;   // column
    const float v = red[0][t] + red[1][t] + red[2][t] + red[3][t];
    atomicAdd(out + b * DD + t, v);
}

extern "C" void kernel_launch(void* const* d_in, const int* in_sizes, int n_in,
                              void* d_out, int out_size, void* d_ws, size_t ws_size,
                              hipStream_t stream) {
    const float* x = (const float*)d_in[0];
    const float* w = (const float*)d_in[1];
    // d_in[2] (edge_index) and d_in[3] (batch) are dead w.r.t. the output.
    float* out = (float*)d_out;

    float* score = (float*)d_ws;                       // 131072 f = 512 KiB
    int*   list  = (int*)((char*)d_ws + 512 * 1024);   //  65536 i = 256 KiB
    float* sval  = (float*)((char*)d_ws + 768 * 1024); //  65536 f = 256 KiB

    // out is poisoned 0xAA before every launch; zero it (capture-safe async).
    hipMemsetAsync(out, 0, (size_t)BG * DD * sizeof(float), stream);

    score_kernel<<<BG * NN / RPW / 4, 256, 0, stream>>>(x, w, score);      // 2048 blocks
    select_kernel<<<BG, 256, 0, stream>>>(score, list, sval);              //  256 blocks
    accum_kernel<<<dim3(BG, SPLIT), 256, 0, stream>>>(x, list, sval, out); // 1024 blocks
}

// Round 3
// 219.826 us; speedup vs baseline: 1.0885x; 1.0652x over previous
//
#include <hip/hip_runtime.h>
#include <math.h>
#include <stdint.h>

// Problem constants (match reference)
#define BG 256   // graphs
#define NN 512   // nodes per graph
#define DD 256   // feature dim
#define KK 256   // nodes kept per graph
#define RPW 16   // rows per wave in score kernel
#define SPLIT 8  // row-chunks per graph in accumulate kernel

// ---------------------------------------------------------------------------
// Kernel 1: score[n] = tanh( dot(x[n,:], w) / ||w|| )
// Wave-per-row, float4 loads (64 lanes x 16 B = 1 KiB = one row per load).
// Each wave owns 16 consecutive rows, processed 4 at a time with independent
// shuffle-reduce chains for ILP. At the 128 MiB / ~6 TB/s HBM floor already.
// ---------------------------------------------------------------------------
__global__ __launch_bounds__(256) void score_kernel(const float* __restrict__ x,
                                                    const float* __restrict__ w,
                                                    float* __restrict__ score) {
    const int lane = threadIdx.x & 63;
    const int wid  = blockIdx.x * 4 + (threadIdx.x >> 6);

    const float4 w4 = *reinterpret_cast<const float4*>(w + lane * 4);

    float nw = w4.x * w4.x + w4.y * w4.y + w4.z * w4.z + w4.w * w4.w;
#pragma unroll
    for (int off = 32; off >= 1; off >>= 1) nw += __shfl_xor(nw, off);
    const float inv_nrm = rsqrtf(nw);

    const int base = wid * RPW;
    const float* xp = x + (size_t)base * DD + lane * 4;

#pragma unroll
    for (int r0 = 0; r0 < RPW; r0 += 4) {
        float d0, d1, d2, d3;
        {
            const float4 a = *reinterpret_cast<const float4*>(xp + (size_t)(r0 + 0) * DD);
            const float4 b = *reinterpret_cast<const float4*>(xp + (size_t)(r0 + 1) * DD);
            const float4 c = *reinterpret_cast<const float4*>(xp + (size_t)(r0 + 2) * DD);
            const float4 e = *reinterpret_cast<const float4*>(xp + (size_t)(r0 + 3) * DD);
            d0 = fmaf(a.x, w4.x, fmaf(a.y, w4.y, fmaf(a.z, w4.z, a.w * w4.w)));
            d1 = fmaf(b.x, w4.x, fmaf(b.y, w4.y, fmaf(b.z, w4.z, b.w * w4.w)));
            d2 = fmaf(c.x, w4.x, fmaf(c.y, w4.y, fmaf(c.z, w4.z, c.w * w4.w)));
            d3 = fmaf(e.x, w4.x, fmaf(e.y, w4.y, fmaf(e.z, w4.z, e.w * w4.w)));
        }
#pragma unroll
        for (int off = 32; off >= 1; off >>= 1) {
            d0 += __shfl_xor(d0, off);
            d1 += __shfl_xor(d1, off);
            d2 += __shfl_xor(d2, off);
            d3 += __shfl_xor(d3, off);
        }
        if (lane == 0) {
            float4 o;
            o.x = tanhf(d0 * inv_nrm);
            o.y = tanhf(d1 * inv_nrm);
            o.z = tanhf(d2 * inv_nrm);
            o.w = tanhf(d3 * inv_nrm);
            *reinterpret_cast<float4*>(score + base + r0) = o;
        }
    }
}

// ---------------------------------------------------------------------------
// Kernel 2: per-graph exact top-K via single-wave radix select. One wave per
// graph holds all 512 scores in registers (8/lane). MSB-first binary search
// on order-flipped float bits; counts via __ballot + __popcll (no LDS, no
// barriers, no shuffle chains). Exact-K tie handling matching jax.lax.top_k
// (stable: lower index wins on equal values; global index order is
// lane-major = lane*8+j, so ballot lane-prefix masks give tie ranks).
// Emits compacted index list + score*(1/K) per graph.
// ---------------------------------------------------------------------------
__device__ __forceinline__ uint32_t flip_f32(float f) {
    const uint32_t u = __float_as_uint(f);
    return (u & 0x80000000u) ? ~u : (u | 0x80000000u);   // order-preserving map
}

__global__ __launch_bounds__(64) void select_kernel(const float* __restrict__ score,
                                                    int* __restrict__ list,
                                                    float* __restrict__ sval) {
    const int b    = blockIdx.x;
    const int lane = threadIdx.x;          // 0..63, one full wave
    const float* sg = score + b * NN;

    float s[8];
    const float4 a0 = *reinterpret_cast<const float4*>(sg + lane * 8);
    const float4 a1 = *reinterpret_cast<const float4*>(sg + lane * 8 + 4);
    s[0] = a0.x; s[1] = a0.y; s[2] = a0.z; s[3] = a0.w;
    s[4] = a1.x; s[5] = a1.y; s[6] = a1.z; s[7] = a1.w;

    uint32_t u[8];
#pragma unroll
    for (int j = 0; j < 8; ++j) u[j] = flip_f32(s[j]);

    // MSB-first radix binary search: p ends as the exact K-th largest key.
    uint32_t p = 0u;
    for (int bit = 31; bit >= 0; --bit) {
        const uint32_t cand = p | (1u << bit);
        int cnt = 0;
#pragma unroll
        for (int j = 0; j < 8; ++j)
            cnt += __popcll(__ballot(u[j] >= cand));
        if (cnt >= KK) p = cand;
    }

    // Strictly-greater count and tie ballots.
    unsigned long long bt[8];
    int cgt = 0;
#pragma unroll
    for (int j = 0; j < 8; ++j) {
        cgt += __popcll(__ballot(u[j] > p));
        bt[j] = __ballot(u[j] == p);
    }
    const int need = KK - cgt;   // ties at p to take, lowest global index first
    const unsigned long long below = ((unsigned long long)1 << lane) - 1ull;

    // Tie rank of this lane's first tie = ties in all lower lanes (any j).
    int tie_rank = 0;
#pragma unroll
    for (int j = 0; j < 8; ++j) tie_rank += __popcll(bt[j] & below);

    bool selj[8];
    int ntie = 0;
#pragma unroll
    for (int j = 0; j < 8; ++j) {
        const bool gt  = (u[j] > p);
        const bool tie = (u[j] == p);
        selj[j] = gt || (tie && (tie_rank + ntie) < need);
        ntie += tie ? 1 : 0;
    }

    // Compaction slots: prefix over lower lanes' selected counts (ballots),
    // plus local running count. Order in the list is irrelevant for the sum.
    unsigned long long bs[8];
#pragma unroll
    for (int j = 0; j < 8; ++j) bs[j] = __ballot(selj[j]);
    int slot = 0;
#pragma unroll
    for (int j = 0; j < 8; ++j) slot += __popcll(bs[j] & below);

    int*   lb = list + b * KK;
    float* sb = sval + b * KK;
#pragma unroll
    for (int j = 0; j < 8; ++j) {
        if (selj[j]) {
            lb[slot] = lane * 8 + j;
            sb[slot] = s[j] * (1.0f / (float)KK);   // fold mean divisor
            ++slot;
        }
    }
}

// ---------------------------------------------------------------------------
// Kernel 3: gated mean accumulate. Grid (BG, SPLIT=8) = 2048 blocks -> 8
// blocks/CU = 32 waves/CU (max occupancy) to hide L3 latency. Each wave
// handles 8 selected rows: indices/scores preloaded to registers, then
// full-row float4 loads (1 KiB per instruction). Cross-wave LDS reduce,
// one float atomicAdd per column (out pre-zeroed).
// ---------------------------------------------------------------------------
__global__ __launch_bounds__(256) void accum_kernel(const float* __restrict__ x,
                                                    const int* __restrict__ list,
                                                    const float* __restrict__ sval,
                                                    float* __restrict__ out) {
    const int b    = blockIdx.x;
    const int sc   = blockIdx.y;
    const int wv   = threadIdx.x >> 6;
    const int lane = threadIdx.x & 63;
    const int kk0  = sc * (KK / SPLIT) + wv * (KK / SPLIT / 4);   // 8 rows/wave

    const float* xg = x + (size_t)b * NN * DD;
    const int*   lb = list + b * KK + kk0;
    const float* sb = sval + b * KK + kk0;

    int   idx[KK / SPLIT / 4];
    float sv[KK / SPLIT / 4];
#pragma unroll
    for (int r = 0; r < KK / SPLIT / 4; ++r) { idx[r] = lb[r]; sv[r] = sb[r]; }

    float4 acc = {0.f, 0.f, 0.f, 0.f};
#pragma unroll
    for (int r = 0; r < KK / SPLIT / 4; ++r) {
        const float4 x4 = *reinterpret_cast<const float4*>(xg + (size_t)idx[r] * DD + lane * 4);
        acc.x = fmaf(sv[r], x4.x, acc.x);
        acc.y = fmaf(sv[r], x4.y, acc.y);
        acc.z = fmaf(sv[r], x4.z, acc.z);
        acc.w = fmaf(sv[r], x4.w, acc.w);
    }

    __shared__ float red[4][DD];
    *reinterpret_cast<float4*>(&red[wv][lane * 4]) = acc;
    __syncthreads();

    const int t = threadIdx.x;   // output column
    const float v = red[0][t] + red[1][t] + red[2][t] + red[3][t];
    atomicAdd(out + b * DD + t, v);
}

extern "C" void kernel_launch(void* const* d_in, const int* in_sizes, int n_in,
                              void* d_out, int out_size, void* d_ws, size_t ws_size,
                              hipStream_t stream) {
    const float* x = (const float*)d_in[0];
    const float* w = (const float*)d_in[1];
    // d_in[2] (edge_index) and d_in[3] (batch) are dead w.r.t. the output.
    float* out = (float*)d_out;

    float* score = (float*)d_ws;                       // 131072 f = 512 KiB
    int*   list  = (int*)((char*)d_ws + 512 * 1024);   //  65536 i = 256 KiB
    float* sval  = (float*)((char*)d_ws + 768 * 1024); //  65536 f = 256 KiB

    // out is poisoned 0xAA before every launch; zero it (capture-safe async).
    hipMemsetAsync(out, 0, (size_t)BG * DD * sizeof(float), stream);

    score_kernel<<<BG * NN / RPW / 4, 256, 0, stream>>>(x, w, score);       // 2048 blocks
    select_kernel<<<BG, 64, 0, stream>>>(score, list, sval);                //  256 blocks, 1 wave each
    accum_kernel<<<dim3(BG, SPLIT), 256, 0, stream>>>(x, list, sval, out);  // 2048 blocks
}

// Round 4
// 210.809 us; speedup vs baseline: 1.1350x; 1.0428x over previous
//
#include <hip/hip_runtime.h>
#include <math.h>
#include <stdint.h>

// Problem constants (match reference)
#define BG 256   // graphs
#define NN 512   // nodes per graph
#define DD 256   // feature dim
#define KK 256   // nodes kept per graph
#define WAVES 16 // waves per block (1024 threads)

// ---------------------------------------------------------------------------
// Fully fused TopKPooling + global_mean_pool: ONE kernel, one block per graph
// (256 blocks x 1024 threads = exactly 1 block/CU, 16 waves/CU).
//
// Phase 1 (score): wave w computes scores for rows [32w, 32w+32) of its
//   graph: full-row float4 loads (64 lanes x 16 B = 1 KiB = one row per
//   instruction), 8 independent dot/shuffle-reduce chains for HBM latency
//   hiding. tanh computed redundantly on all lanes (SIMD, same cost as one
//   lane). Scores live in LDS only — no global round-trip.
// Phase 2 (select): wave 0 runs exact top-K radix select on order-flipped
//   float bits via __ballot/__popcll (no barriers inside). Tie handling
//   matches jax.lax.top_k (stable: lowest index wins). Compacted
//   (index, score/K) lists stay in LDS.
// Phase 3 (accum): wave w accumulates 16 selected rows with full-row float4
//   loads (these rows were read in phase 1 -> L2/L3 hits), cross-wave LDS
//   reduce, direct store. No atomics, no out-zeroing memset, no workspace.
// ---------------------------------------------------------------------------
__device__ __forceinline__ uint32_t flip_f32(float f) {
    const uint32_t u = __float_as_uint(f);
    return (u & 0x80000000u) ? ~u : (u | 0x80000000u);   // order-preserving map
}

__global__ __launch_bounds__(1024) void topk_pool_fused(const float* __restrict__ x,
                                                        const float* __restrict__ w,
                                                        float* __restrict__ out) {
    __shared__ float s[NN];           // scores, indexed by node-in-graph
    __shared__ int   lidx[KK];        // selected node indices (order arbitrary)
    __shared__ float lval[KK];        // selected score * (1/K)
    __shared__ float red[WAVES][DD];  // cross-wave reduction buffer

    const int b    = blockIdx.x;
    const int wv   = threadIdx.x >> 6;
    const int lane = threadIdx.x & 63;

    const float4 w4 = *reinterpret_cast<const float4*>(w + lane * 4);
    float nw = fmaf(w4.x, w4.x, fmaf(w4.y, w4.y, fmaf(w4.z, w4.z, w4.w * w4.w)));
#pragma unroll
    for (int off = 32; off >= 1; off >>= 1) nw += __shfl_xor(nw, off);
    const float inv_nrm = rsqrtf(nw);

    const float* xg = x + (size_t)b * NN * DD;

    // ---------------- Phase 1: scores for rows [wv*32, wv*32+32) -----------
    {
        const float* xp = xg + (size_t)(wv * 32) * DD + lane * 4;
#pragma unroll
        for (int r0 = 0; r0 < 32; r0 += 8) {
            float d[8];
#pragma unroll
            for (int j = 0; j < 8; ++j) {
                const float4 a = *reinterpret_cast<const float4*>(xp + (size_t)(r0 + j) * DD);
                d[j] = fmaf(a.x, w4.x, fmaf(a.y, w4.y, fmaf(a.z, w4.z, a.w * w4.w)));
            }
#pragma unroll
            for (int off = 32; off >= 1; off >>= 1) {
#pragma unroll
                for (int j = 0; j < 8; ++j) d[j] += __shfl_xor(d[j], off);
            }
#pragma unroll
            for (int j = 0; j < 8; ++j) d[j] = tanhf(d[j] * inv_nrm);
            if (lane == 0) {
                float4 o0 = {d[0], d[1], d[2], d[3]};
                float4 o1 = {d[4], d[5], d[6], d[7]};
                *reinterpret_cast<float4*>(&s[wv * 32 + r0])     = o0;
                *reinterpret_cast<float4*>(&s[wv * 32 + r0 + 4]) = o1;
            }
        }
    }
    __syncthreads();

    // ---------------- Phase 2: exact top-K radix select (wave 0) -----------
    if (wv == 0) {
        float sv[8];
        const float4 a0 = *reinterpret_cast<const float4*>(&s[lane * 8]);
        const float4 a1 = *reinterpret_cast<const float4*>(&s[lane * 8 + 4]);
        sv[0] = a0.x; sv[1] = a0.y; sv[2] = a0.z; sv[3] = a0.w;
        sv[4] = a1.x; sv[5] = a1.y; sv[6] = a1.z; sv[7] = a1.w;

        uint32_t u[8];
#pragma unroll
        for (int j = 0; j < 8; ++j) u[j] = flip_f32(sv[j]);

        // MSB-first binary search: p ends as the exact K-th largest key.
        uint32_t p = 0u;
        for (int bit = 31; bit >= 0; --bit) {
            const uint32_t cand = p | (1u << bit);
            int cnt = 0;
#pragma unroll
            for (int j = 0; j < 8; ++j)
                cnt += __popcll(__ballot(u[j] >= cand));
            if (cnt >= KK) p = cand;
        }

        unsigned long long bt[8];
        int cgt = 0;
#pragma unroll
        for (int j = 0; j < 8; ++j) {
            cgt += __popcll(__ballot(u[j] > p));
            bt[j] = __ballot(u[j] == p);
        }
        const int need = KK - cgt;   // ties at p to take, lowest index first
        const unsigned long long below = ((unsigned long long)1 << lane) - 1ull;

        int tie_rank = 0;
#pragma unroll
        for (int j = 0; j < 8; ++j) tie_rank += __popcll(bt[j] & below);

        bool selj[8];
        int ntie = 0;
#pragma unroll
        for (int j = 0; j < 8; ++j) {
            const bool gt  = (u[j] > p);
            const bool tie = (u[j] == p);
            selj[j] = gt || (tie && (tie_rank + ntie) < need);
            ntie += tie ? 1 : 0;
        }

        unsigned long long bs[8];
#pragma unroll
        for (int j = 0; j < 8; ++j) bs[j] = __ballot(selj[j]);
        int slot = 0;
#pragma unroll
        for (int j = 0; j < 8; ++j) slot += __popcll(bs[j] & below);

#pragma unroll
        for (int j = 0; j < 8; ++j) {
            if (selj[j]) {
                lidx[slot] = lane * 8 + j;
                lval[slot] = sv[j] * (1.0f / (float)KK);   // fold mean divisor
                ++slot;
            }
        }
    }
    __syncthreads();

    // ---------------- Phase 3: gated accumulate + reduce -------------------
    int   idx[KK / WAVES];
    float svv[KK / WAVES];
#pragma unroll
    for (int r = 0; r < KK / WAVES; ++r) {   // 16 rows per wave
        idx[r] = lidx[wv * (KK / WAVES) + r];
        svv[r] = lval[wv * (KK / WAVES) + r];
    }

    float4 acc = {0.f, 0.f, 0.f, 0.f};
#pragma unroll
    for (int r = 0; r < KK / WAVES; ++r) {
        const float4 x4 = *reinterpret_cast<const float4*>(xg + (size_t)idx[r] * DD + lane * 4);
        acc.x = fmaf(svv[r], x4.x, acc.x);
        acc.y = fmaf(svv[r], x4.y, acc.y);
        acc.z = fmaf(svv[r], x4.z, acc.z);
        acc.w = fmaf(svv[r], x4.w, acc.w);
    }
    *reinterpret_cast<float4*>(&red[wv][lane * 4]) = acc;
    __syncthreads();

    if (threadIdx.x < DD) {
        const int t = threadIdx.x;
        float v = 0.f;
#pragma unroll
        for (int wq = 0; wq < WAVES; ++wq) v += red[wq][t];
        out[b * DD + t] = v;
    }
}

extern "C" void kernel_launch(void* const* d_in, const int* in_sizes, int n_in,
                              void* d_out, int out_size, void* d_ws, size_t ws_size,
                              hipStream_t stream) {
    const float* x = (const float*)d_in[0];
    const float* w = (const float*)d_in[1];
    // d_in[2] (edge_index) and d_in[3] (batch) are dead w.r.t. the output.
    float* out = (float*)d_out;
    (void)d_ws; (void)ws_size;

    topk_pool_fused<<<BG, 1024, 0, stream>>>(x, w, out);   // 256 blocks = 1/CU
}